// Round 12
// baseline (211.134 us; speedup 1.0000x reference)
//
#include <hip/hip_runtime.h>
#include <hip/hip_bf16.h>
#include <stdint.h>

#define T_SEQ 4096
#define NH 12

#if __has_builtin(__builtin_amdgcn_exp2f)
#define EXP2F __builtin_amdgcn_exp2f
#else
#define EXP2F exp2f
#endif

typedef __attribute__((ext_vector_type(4))) float f32x4;
typedef __attribute__((ext_vector_type(8))) __bf16 bf16x8;

__device__ inline ushort f2b(float f) {
  __hip_bfloat16 h = __float2bfloat16(f);
  return *reinterpret_cast<ushort*>(&h);
}
__device__ inline float b2f(ushort u) {
  union { uint i; float f; } v; v.i = (uint)u << 16; return v.f;
}

__device__ inline void gload_lds16(const void* g, void* lds) {
  auto g1 = (const __attribute__((address_space(1))) uint32_t*)(uintptr_t)g;
  auto l3 = (__attribute__((address_space(3))) uint32_t*)(uintptr_t)lds;
  __builtin_amdgcn_global_load_lds(g1, l3, 16, 0, 0);
}

// ---------------- fused prep: 3x fp32->bf16 convert + RoPE tables, one launch ----------------
__global__ __launch_bounds__(256) void prep_all(const float* __restrict__ x,
                                                const float* __restrict__ wA,
                                                const float* __restrict__ wP,
                                                ushort* __restrict__ xb,
                                                ushort* __restrict__ wAb,
                                                ushort* __restrict__ wPb,
                                                float* __restrict__ cosT,
                                                float* __restrict__ sinT) {
  const int u = blockIdx.x * blockDim.x + threadIdx.x;
  if (u < 688128) {
    const float* src;
    ushort* dst;
    long i;
    if (u < 393216)      { src = x;  dst = xb;  i = u; }
    else if (u < 614400) { src = wA; dst = wAb; i = u - 393216; }
    else                 { src = wP; dst = wPb; i = u - 614400; }
    const float4* s4 = (const float4*)src;
    float4 a = s4[i * 2], b = s4[i * 2 + 1];
    uint4 o;
    o.x = (uint)f2b(a.x) | ((uint)f2b(a.y) << 16);
    o.y = (uint)f2b(a.z) | ((uint)f2b(a.w) << 16);
    o.z = (uint)f2b(b.x) | ((uint)f2b(b.y) << 16);
    o.w = (uint)f2b(b.z) | ((uint)f2b(b.w) << 16);
    *(uint4*)(dst + i * 8) = o;
  } else if (u < 704512) {
    const int base = (u - 688128) * 8;   // i = t*32 + d
    const int t = base >> 5;
#pragma unroll
    for (int j = 0; j < 8; ++j) {
      const int d = (base + j) & 31;
      float theta = 1.0f / powf(10000.0f, (float)d * (1.0f / 32.0f));
      float a = (float)t * theta;
      cosT[base + j] = cosf(a);
      sinT[base + j] = sinf(a);
    }
  }
}

// ---------------- GEMM1 + fused RoPE/reorder epilogue (1D grid, XCD-swizzled) ----------------
__global__ __launch_bounds__(256) void gemm_qkv(const ushort* __restrict__ A,
                                                const ushort* __restrict__ B,
                                                const float* __restrict__ cosT,
                                                const float* __restrict__ sinT,
                                                ushort* __restrict__ Q,
                                                ushort* __restrict__ Kb,
                                                ushort* __restrict__ Vt) {
  __shared__ ushort As[128 * 64];
  __shared__ ushort Bs[128 * 64];
  const int wg = (blockIdx.x & 7) * 72 + (blockIdx.x >> 3);
  const int bx = wg % 18;
  const int by = wg / 18;
  const int t = threadIdx.x;
  const int w = t >> 6, l = t & 63;
  const int lo = l & 15, hi = l >> 4;
  const int wr = w >> 1, wc = w & 1;
  const long arow = (long)by * 128;
  const long brow = (long)bx * 128;
  const int K = 768;
  f32x4 acc[4][4] = {};
  for (int k0 = 0; k0 < K; k0 += 64) {
    for (int i = 0; i < 4; ++i) {
      int e = i * 2048 + t * 8;
      int r = e >> 6, c = e & 63;
      const ushort* ga = A + (arow + r) * (long)K + k0 + c;
      const ushort* gb = B + (brow + r) * (long)K + k0 + c;
      uint32_t ldsoff = i * 4096 + w * 1024;
      gload_lds16(ga, (char*)As + ldsoff);
      gload_lds16(gb, (char*)Bs + ldsoff);
    }
    __syncthreads();
    for (int kk = 0; kk < 2; ++kk) {
      bf16x8 af[4], bfr[4];
      for (int m = 0; m < 4; ++m)
        af[m] = *(const bf16x8*)&As[(wr * 64 + m * 16 + lo) * 64 + kk * 32 + hi * 8];
      for (int n = 0; n < 4; ++n)
        bfr[n] = *(const bf16x8*)&Bs[(wc * 64 + n * 16 + lo) * 64 + kk * 32 + hi * 8];
      for (int m = 0; m < 4; ++m)
        for (int n = 0; n < 4; ++n)
          acc[m][n] = __builtin_amdgcn_mfma_f32_16x16x32_bf16(af[m], bfr[n], acc[m][n], 0, 0, 0);
    }
    __syncthreads();
  }
  // ---- fused epilogue ----
  const int rq = bx / 6;                 // 0=Q, 1=K, 2=V
  const int h  = (bx % 6) * 2 + wc;      // head for this thread's cols
  const long hT = (long)h * T_SEQ;
  if (rq < 2) {
    ushort* dst = (rq == 0) ? Q : Kb;
    const float qsc = (rq == 0) ? 0.125f * 1.44269504f : 1.0f;
#pragma unroll
    for (int m = 0; m < 4; ++m)
#pragma unroll
      for (int r = 0; r < 4; ++r) {
        const long trow = arow + wr * 64 + m * 16 + hi * 4 + r;
        ushort* rowp = dst + (hT + trow) * 64;
        const float* cp = cosT + trow * 32;
        const float* sp = sinT + trow * 32;
#pragma unroll
        for (int n = 0; n < 2; ++n) {
          const int dd = n * 16 + lo;
          const float cs = cp[dd], sn = sp[dd];
          const float a = acc[m][n][r], b = acc[m][n + 2][r];
          rowp[dd]      = f2b((a * cs - b * sn) * qsc);
          rowp[dd + 32] = f2b((a * sn + b * cs) * qsc);
        }
      }
  } else {
#pragma unroll
    for (int m = 0; m < 4; ++m) {
      const long trow0 = arow + wr * 64 + m * 16 + hi * 4;
#pragma unroll
      for (int n = 0; n < 4; ++n) {
        const int d = n * 16 + lo;
        uint2 pk;
        pk.x = (uint)f2b(acc[m][n][0]) | ((uint)f2b(acc[m][n][1]) << 16);
        pk.y = (uint)f2b(acc[m][n][2]) | ((uint)f2b(acc[m][n][3]) << 16);
        *(uint2*)(Vt + ((long)h * 64 + d) * T_SEQ + trow0) = pk;
      }
    }
  }
}

// ---------------- bf16 GEMM, C = A * B^T (fp32 out; out-proj; 1D grid, XCD-swizzled) ----------------
__global__ __launch_bounds__(256) void gemm_bt(const ushort* __restrict__ A,
                                               const ushort* __restrict__ B,
                                               float* __restrict__ C,
                                               int M, int N, int K) {
  __shared__ ushort As[128 * 64];
  __shared__ ushort Bs[128 * 64];
  const int nbx = N >> 7;
  const int nwg = (M >> 7) * nbx;
  const int cpx = nwg >> 3;
  const int wg = (blockIdx.x & 7) * cpx + (blockIdx.x >> 3);
  const int bx = wg % nbx;
  const int by = wg / nbx;
  const int t = threadIdx.x;
  const int w = t >> 6, l = t & 63;
  const int lo = l & 15, hi = l >> 4;
  const int wr = w >> 1, wc = w & 1;
  const long arow = (long)by * 128;
  const long brow = (long)bx * 128;
  f32x4 acc[4][4] = {};
  for (int k0 = 0; k0 < K; k0 += 64) {
    for (int i = 0; i < 4; ++i) {
      int e = i * 2048 + t * 8;
      int r = e >> 6, c = e & 63;
      const ushort* ga = A + (arow + r) * (long)K + k0 + c;
      const ushort* gb = B + (brow + r) * (long)K + k0 + c;
      uint32_t ldsoff = i * 4096 + w * 1024;
      gload_lds16(ga, (char*)As + ldsoff);
      gload_lds16(gb, (char*)Bs + ldsoff);
    }
    __syncthreads();
    for (int kk = 0; kk < 2; ++kk) {
      bf16x8 af[4], bfr[4];
      for (int m = 0; m < 4; ++m)
        af[m] = *(const bf16x8*)&As[(wr * 64 + m * 16 + lo) * 64 + kk * 32 + hi * 8];
      for (int n = 0; n < 4; ++n)
        bfr[n] = *(const bf16x8*)&Bs[(wc * 64 + n * 16 + lo) * 64 + kk * 32 + hi * 8];
      for (int m = 0; m < 4; ++m)
        for (int n = 0; n < 4; ++n)
          acc[m][n] = __builtin_amdgcn_mfma_f32_16x16x32_bf16(af[m], bfr[n], acc[m][n], 0, 0, 0);
    }
    __syncthreads();
  }
  for (int m = 0; m < 4; ++m) {
    long row0 = arow + wr * 64 + m * 16 + hi * 4;
    for (int n = 0; n < 4; ++n) {
      long col = brow + wc * 64 + n * 16 + lo;
      for (int r = 0; r < 4; ++r)
        C[(row0 + r) * (long)N + col] = acc[m][n][r];
    }
  }
}

// ---------------- flash attention: 8-wave blocks, K double-buffered in LDS, V direct-from-global ----------------
// V tile (8KB/iter) is L1/L2-resident and shared by all 8 waves -> staging it was pure
// overhead (guide m169); dropping Vs cuts LDS 50->34.8KB => 4 blocks/CU.
// V fragment loads issued FIRST in the compute section so L2 latency hides under QK^T+softmax.
// launch_bounds (512,4): VGPR cap 128 -- (512,6) forced VGPR=40 and spilled ~150MB/dispatch.
__global__ __launch_bounds__(512, 4) void flash_attn(const ushort* __restrict__ Q,
                                                     const ushort* __restrict__ Kb,
                                                     const ushort* __restrict__ Vt,
                                                     char* __restrict__ part) {
  const int n    = blockIdx.x;
  const int work = (n & 7) * 192 + (n >> 3);   // XCD-bijective: one (h,c)'s blocks on one XCD
  const int pair = work >> 5;                   // 0..47 = h*4 + c
  const int qb   = work & 31;                   // 128-row q-tile
  const int h    = pair >> 2;
  const int c    = pair & 3;
  const int kstart  = c << 10;
  const int blk_lim = qb * 128 + 128;
  if (kstart >= blk_lim) return;
  const int kend = (kstart + 1024 < blk_lim) ? kstart + 1024 : blk_lim;

  __shared__ ushort Ks[2][4096];   // [64 rows][64 bf16], XOR-swizzled content
  __shared__ ushort P[8][16][72];

  const int t = threadIdx.x;
  const int w = t >> 6, l = t & 63;
  const int lo = l & 15, hi = l >> 4, lo7 = l & 7;
  const int qrow0 = qb * 128 + w * 16;
  const int qlim  = qrow0 + 16;
  const int qabs  = qrow0 + lo;
  const long hT   = (long)h * T_SEQ;
  const long hT64 = (long)h * 64;

  const int srow8 = l >> 3;               // 0..7: row within this wave's 8-row group
  const int row_w = w * 8 + srow8;        // 0..63: tile row this lane stages
  const int schk  = (l & 7) ^ srow8;      // inverse-swizzled source 16B-chunk

  bf16x8 qf0, qf1;
  {
    const ushort* qp = Q + (hT + qrow0 + lo) * 64 + hi * 8;
    qf0 = *(const bf16x8*)qp;
    qf1 = *(const bf16x8*)(qp + 32);
  }
  f32x4 o[4] = {};
  float m = -1e30f, lsum = 0.0f;

#define STAGE(buf, k0s)                                                         \
  {                                                                             \
    gload_lds16(Kb + (hT + (k0s) + row_w) * 64 + schk * 8,                      \
                (char*)&Ks[buf][0] + w * 1024);                                 \
  }

  STAGE(0, kstart);
  __syncthreads();
  int buf = 0;

  for (int k0 = kstart; k0 < kend; k0 += 64) {
    if (k0 + 64 < kend) STAGE(buf ^ 1, k0 + 64);
    if (k0 < qlim) {
      const ushort* kt_ = &Ks[buf][0];
      // --- V fragments from GLOBAL first: L2 latency overlaps QK^T + softmax ---
      bf16x8 vf[8];
#pragma unroll
      for (int dt = 0; dt < 4; ++dt)
#pragma unroll
        for (int cc = 0; cc < 2; ++cc)
          vf[dt * 2 + cc] =
              *(const bf16x8*)(Vt + (hT64 + dt * 16 + lo) * T_SEQ + k0 + cc * 32 + hi * 8);
      // --- S^T = K . Q^T from swizzled LDS ---
      f32x4 s[4];
#pragma unroll
      for (int kt = 0; kt < 4; ++kt) {
        int rr = kt * 16 + lo;
        bf16x8 ka = *(const bf16x8*)(kt_ + rr * 64 + ((hi ^ lo7) * 8));
        bf16x8 kc = *(const bf16x8*)(kt_ + rr * 64 + (((4 + hi) ^ lo7) * 8));
        f32x4 a = {};
        a = __builtin_amdgcn_mfma_f32_16x16x32_bf16(ka, qf0, a, 0, 0, 0);
        a = __builtin_amdgcn_mfma_f32_16x16x32_bf16(kc, qf1, a, 0, 0, 0);
        s[kt] = a;
      }
      // --- causal mask (diagonal tiles only) ---
      if (k0 + 64 > qrow0) {
#pragma unroll
        for (int kt = 0; kt < 4; ++kt)
#pragma unroll
          for (int r = 0; r < 4; ++r) {
            int key = k0 + kt * 16 + hi * 4 + r;
            if (key > qabs) s[kt][r] = -1e30f;
          }
      }
      // --- row max: 15 in-lane fmax + 2 shfl ---
      float mt = s[0][0];
#pragma unroll
      for (int kt = 0; kt < 4; ++kt)
#pragma unroll
        for (int r = 0; r < 4; ++r) mt = fmaxf(mt, s[kt][r]);
      mt = fmaxf(mt, __shfl_xor(mt, 16));
      mt = fmaxf(mt, __shfl_xor(mt, 32));
      // --- defer-max rescale (THR=8 in log2 domain) ---
      if (!__all(mt - m <= 8.0f)) {
        float mn = fmaxf(m, mt);
        float alpha = EXP2F(m - mn);
        m = mn;
        lsum *= alpha;
#pragma unroll
        for (int r = 0; r < 4; ++r) {
          float ar = __shfl(alpha, hi * 4 + r);
#pragma unroll
          for (int dt = 0; dt < 4; ++dt) o[dt][r] *= ar;
        }
      }
      // --- exp2 + per-lane sum + pack P ---
#pragma unroll
      for (int kt = 0; kt < 4; ++kt) {
        float p0 = EXP2F(s[kt][0] - m);
        float p1 = EXP2F(s[kt][1] - m);
        float p2 = EXP2F(s[kt][2] - m);
        float p3 = EXP2F(s[kt][3] - m);
        lsum += (p0 + p1) + (p2 + p3);
        uint2 pk;
        pk.x = (uint)f2b(p0) | ((uint)f2b(p1) << 16);
        pk.y = (uint)f2b(p2) | ((uint)f2b(p3) << 16);
        *(uint2*)&P[w][lo][kt * 16 + hi * 4] = pk;
      }
      asm volatile("s_waitcnt lgkmcnt(0)" ::: "memory");
      // --- PV from registers ---
#pragma unroll
      for (int cc = 0; cc < 2; ++cc) {
        bf16x8 pa = *(const bf16x8*)&P[w][lo][cc * 32 + hi * 8];
#pragma unroll
        for (int dt = 0; dt < 4; ++dt)
          o[dt] = __builtin_amdgcn_mfma_f32_16x16x32_bf16(pa, vf[dt * 2 + cc], o[dt], 0, 0, 0);
      }
    }
    __syncthreads();
    buf ^= 1;
  }
#undef STAGE

  // --- write partial (unnormalized); wave active iff kstart < qlim ---
  if (kstart < qlim) {
    lsum += __shfl_xor(lsum, 16);
    lsum += __shfl_xor(lsum, 32);
    const int qg = qb * 8 + w;
    char* pb = part + (((long)(h * 256 + qg)) * 4 + c) * 2176;
    ushort* po = (ushort*)pb;
#pragma unroll
    for (int dt = 0; dt < 4; ++dt)
#pragma unroll
      for (int r = 0; r < 4; ++r)
        po[(hi * 4 + r) * 64 + dt * 16 + lo] = f2b(o[dt][r]);
    if (hi == 0) {
      ((float*)(pb + 2048))[lo] = m;
      ((float*)(pb + 2112))[lo] = lsum;
    }
  }
}

// ---------------- split-K combine ----------------
__global__ __launch_bounds__(64) void flash_combine(const char* __restrict__ part,
                                                    ushort* __restrict__ Y) {
  const int qg = blockIdx.x, h = blockIdx.y, d = threadIdx.x;
  const int qrow0 = qg * 16;
  const int nch = (qrow0 + 16 + 1023) >> 10;
  const char* ub = part + ((long)(h * 256 + qg)) * 4 * 2176;
  float Mg[16];
#pragma unroll
  for (int r = 0; r < 16; ++r) Mg[r] = -1e30f;
  for (int cc = 0; cc < nch; ++cc) {
    const float* mp = (const float*)(ub + cc * 2176 + 2048);
#pragma unroll
    for (int r = 0; r < 16; ++r) Mg[r] = fmaxf(Mg[r], mp[r]);
  }
  float acc[16], lg[16];
#pragma unroll
  for (int r = 0; r < 16; ++r) { acc[r] = 0.0f; lg[r] = 0.0f; }
  for (int cc = 0; cc < nch; ++cc) {
    const ushort* op = (const ushort*)(ub + cc * 2176);
    const float* mp = (const float*)(ub + cc * 2176 + 2048);
    const float* lp = (const float*)(ub + cc * 2176 + 2112);
#pragma unroll
    for (int r = 0; r < 16; ++r) {
      float wgt = EXP2F(mp[r] - Mg[r]);
      acc[r] += wgt * b2f(op[r * 64 + d]);
      lg[r]  += wgt * lp[r];
    }
  }
#pragma unroll
  for (int r = 0; r < 16; ++r)
    Y[(long)(qrow0 + r) * 768 + h * 64 + d] = f2b(acc[r] / lg[r]);
}

extern "C" void kernel_launch(void* const* d_in, const int* in_sizes, int n_in,
                              void* d_out, int out_size, void* d_ws, size_t ws_size,
                              hipStream_t stream) {
  const float* x      = (const float*)d_in[0];
  const float* w_attn = (const float*)d_in[1];
  const float* w_proj = (const float*)d_in[2];
  float* out = (float*)d_out;
  char* ws = (char*)d_ws;

  ushort* xb   = (ushort*)(ws);                 // 4096*768
  ushort* wAb  = (ushort*)(ws + 6291456);       // 2304*768
  ushort* wPb  = (ushort*)(ws + 9830400);       // 768*768
  float*  cosT = (float*)(ws + 11010048);       // 4096*32
  float*  sinT = (float*)(ws + 11534336);
  char*   partR = (ws + 12058624);              // flash split-K partials
  ushort* Qb   = (ushort*)(ws + 49807360);      // [12][4096][64]
  ushort* Kbb  = (ushort*)(ws + 56098816);
  ushort* Vt   = (ushort*)(ws + 62390272);      // [12][64][4096]
  ushort* Yb   = (ushort*)(ws + 68681728);      // [4096][768]

  prep_all<<<2752, 256, 0, stream>>>(x, w_attn, w_proj, xb, wAb, wPb, cosT, sinT);
  gemm_qkv<<<576, 256, 0, stream>>>(xb, wAb, cosT, sinT, Qb, Kbb, Vt);
  flash_attn<<<1536, 512, 0, stream>>>(Qb, Kbb, Vt, partR);
  flash_combine<<<dim3(256, NH), 64, 0, stream>>>(partR, Yb);
  gemm_bt<<<192, 256, 0, stream>>>(Yb, wPb, out, 4096, 768, 768);
}

// Round 13
// 134.966 us; speedup vs baseline: 1.5643x; 1.5643x over previous
//
#include <hip/hip_runtime.h>
#include <hip/hip_bf16.h>
#include <stdint.h>

#define T_SEQ 4096
#define NH 12

#if __has_builtin(__builtin_amdgcn_exp2f)
#define EXP2F __builtin_amdgcn_exp2f
#else
#define EXP2F exp2f
#endif

typedef __attribute__((ext_vector_type(4))) float f32x4;
typedef __attribute__((ext_vector_type(8))) __bf16 bf16x8;

__device__ inline ushort f2b(float f) {
  __hip_bfloat16 h = __float2bfloat16(f);
  return *reinterpret_cast<ushort*>(&h);
}
__device__ inline float b2f(ushort u) {
  union { uint i; float f; } v; v.i = (uint)u << 16; return v.f;
}

__device__ inline void gload_lds16(const void* g, void* lds) {
  auto g1 = (const __attribute__((address_space(1))) uint32_t*)(uintptr_t)g;
  auto l3 = (__attribute__((address_space(3))) uint32_t*)(uintptr_t)lds;
  __builtin_amdgcn_global_load_lds(g1, l3, 16, 0, 0);
}

// ---------------- fused prep: 3x fp32->bf16 convert + RoPE tables, one launch ----------------
__global__ __launch_bounds__(256) void prep_all(const float* __restrict__ x,
                                                const float* __restrict__ wA,
                                                const float* __restrict__ wP,
                                                ushort* __restrict__ xb,
                                                ushort* __restrict__ wAb,
                                                ushort* __restrict__ wPb,
                                                float* __restrict__ cosT,
                                                float* __restrict__ sinT) {
  const int u = blockIdx.x * blockDim.x + threadIdx.x;
  if (u < 688128) {
    const float* src;
    ushort* dst;
    long i;
    if (u < 393216)      { src = x;  dst = xb;  i = u; }
    else if (u < 614400) { src = wA; dst = wAb; i = u - 393216; }
    else                 { src = wP; dst = wPb; i = u - 614400; }
    const float4* s4 = (const float4*)src;
    float4 a = s4[i * 2], b = s4[i * 2 + 1];
    uint4 o;
    o.x = (uint)f2b(a.x) | ((uint)f2b(a.y) << 16);
    o.y = (uint)f2b(a.z) | ((uint)f2b(a.w) << 16);
    o.z = (uint)f2b(b.x) | ((uint)f2b(b.y) << 16);
    o.w = (uint)f2b(b.z) | ((uint)f2b(b.w) << 16);
    *(uint4*)(dst + i * 8) = o;
  } else if (u < 704512) {
    const int base = (u - 688128) * 8;   // i = t*32 + d
    const int t = base >> 5;
#pragma unroll
    for (int j = 0; j < 8; ++j) {
      const int d = (base + j) & 31;
      float theta = 1.0f / powf(10000.0f, (float)d * (1.0f / 32.0f));
      float a = (float)t * theta;
      cosT[base + j] = cosf(a);
      sinT[base + j] = sinf(a);
    }
  }
}

// ---------------- GEMM1 + fused RoPE/reorder epilogue (1D grid, XCD-swizzled) ----------------
__global__ __launch_bounds__(256) void gemm_qkv(const ushort* __restrict__ A,
                                                const ushort* __restrict__ B,
                                                const float* __restrict__ cosT,
                                                const float* __restrict__ sinT,
                                                ushort* __restrict__ Q,
                                                ushort* __restrict__ Kb,
                                                ushort* __restrict__ Vt) {
  __shared__ ushort As[128 * 64];
  __shared__ ushort Bs[128 * 64];
  const int wg = (blockIdx.x & 7) * 72 + (blockIdx.x >> 3);
  const int bx = wg % 18;
  const int by = wg / 18;
  const int t = threadIdx.x;
  const int w = t >> 6, l = t & 63;
  const int lo = l & 15, hi = l >> 4;
  const int wr = w >> 1, wc = w & 1;
  const long arow = (long)by * 128;
  const long brow = (long)bx * 128;
  const int K = 768;
  f32x4 acc[4][4] = {};
  for (int k0 = 0; k0 < K; k0 += 64) {
    for (int i = 0; i < 4; ++i) {
      int e = i * 2048 + t * 8;
      int r = e >> 6, c = e & 63;
      const ushort* ga = A + (arow + r) * (long)K + k0 + c;
      const ushort* gb = B + (brow + r) * (long)K + k0 + c;
      uint32_t ldsoff = i * 4096 + w * 1024;
      gload_lds16(ga, (char*)As + ldsoff);
      gload_lds16(gb, (char*)Bs + ldsoff);
    }
    __syncthreads();
    for (int kk = 0; kk < 2; ++kk) {
      bf16x8 af[4], bfr[4];
      for (int m = 0; m < 4; ++m)
        af[m] = *(const bf16x8*)&As[(wr * 64 + m * 16 + lo) * 64 + kk * 32 + hi * 8];
      for (int n = 0; n < 4; ++n)
        bfr[n] = *(const bf16x8*)&Bs[(wc * 64 + n * 16 + lo) * 64 + kk * 32 + hi * 8];
      for (int m = 0; m < 4; ++m)
        for (int n = 0; n < 4; ++n)
          acc[m][n] = __builtin_amdgcn_mfma_f32_16x16x32_bf16(af[m], bfr[n], acc[m][n], 0, 0, 0);
    }
    __syncthreads();
  }
  // ---- fused epilogue ----
  const int rq = bx / 6;                 // 0=Q, 1=K, 2=V
  const int h  = (bx % 6) * 2 + wc;      // head for this thread's cols
  const long hT = (long)h * T_SEQ;
  if (rq < 2) {
    ushort* dst = (rq == 0) ? Q : Kb;
    const float qsc = (rq == 0) ? 0.125f * 1.44269504f : 1.0f;
#pragma unroll
    for (int m = 0; m < 4; ++m)
#pragma unroll
      for (int r = 0; r < 4; ++r) {
        const long trow = arow + wr * 64 + m * 16 + hi * 4 + r;
        ushort* rowp = dst + (hT + trow) * 64;
        const float* cp = cosT + trow * 32;
        const float* sp = sinT + trow * 32;
#pragma unroll
        for (int n = 0; n < 2; ++n) {
          const int dd = n * 16 + lo;
          const float cs = cp[dd], sn = sp[dd];
          const float a = acc[m][n][r], b = acc[m][n + 2][r];
          rowp[dd]      = f2b((a * cs - b * sn) * qsc);
          rowp[dd + 32] = f2b((a * sn + b * cs) * qsc);
        }
      }
  } else {
#pragma unroll
    for (int m = 0; m < 4; ++m) {
      const long trow0 = arow + wr * 64 + m * 16 + hi * 4;
#pragma unroll
      for (int n = 0; n < 4; ++n) {
        const int d = n * 16 + lo;
        uint2 pk;
        pk.x = (uint)f2b(acc[m][n][0]) | ((uint)f2b(acc[m][n][1]) << 16);
        pk.y = (uint)f2b(acc[m][n][2]) | ((uint)f2b(acc[m][n][3]) << 16);
        *(uint2*)(Vt + ((long)h * 64 + d) * T_SEQ + trow0) = pk;
      }
    }
  }
}

// ---------------- bf16 GEMM, C = A * B^T (fp32 out; out-proj; 1D grid, XCD-swizzled) ----------------
__global__ __launch_bounds__(256) void gemm_bt(const ushort* __restrict__ A,
                                               const ushort* __restrict__ B,
                                               float* __restrict__ C,
                                               int M, int N, int K) {
  __shared__ ushort As[128 * 64];
  __shared__ ushort Bs[128 * 64];
  const int nbx = N >> 7;
  const int nwg = (M >> 7) * nbx;
  const int cpx = nwg >> 3;
  const int wg = (blockIdx.x & 7) * cpx + (blockIdx.x >> 3);
  const int bx = wg % nbx;
  const int by = wg / nbx;
  const int t = threadIdx.x;
  const int w = t >> 6, l = t & 63;
  const int lo = l & 15, hi = l >> 4;
  const int wr = w >> 1, wc = w & 1;
  const long arow = (long)by * 128;
  const long brow = (long)bx * 128;
  f32x4 acc[4][4] = {};
  for (int k0 = 0; k0 < K; k0 += 64) {
    for (int i = 0; i < 4; ++i) {
      int e = i * 2048 + t * 8;
      int r = e >> 6, c = e & 63;
      const ushort* ga = A + (arow + r) * (long)K + k0 + c;
      const ushort* gb = B + (brow + r) * (long)K + k0 + c;
      uint32_t ldsoff = i * 4096 + w * 1024;
      gload_lds16(ga, (char*)As + ldsoff);
      gload_lds16(gb, (char*)Bs + ldsoff);
    }
    __syncthreads();
    for (int kk = 0; kk < 2; ++kk) {
      bf16x8 af[4], bfr[4];
      for (int m = 0; m < 4; ++m)
        af[m] = *(const bf16x8*)&As[(wr * 64 + m * 16 + lo) * 64 + kk * 32 + hi * 8];
      for (int n = 0; n < 4; ++n)
        bfr[n] = *(const bf16x8*)&Bs[(wc * 64 + n * 16 + lo) * 64 + kk * 32 + hi * 8];
      for (int m = 0; m < 4; ++m)
        for (int n = 0; n < 4; ++n)
          acc[m][n] = __builtin_amdgcn_mfma_f32_16x16x32_bf16(af[m], bfr[n], acc[m][n], 0, 0, 0);
    }
    __syncthreads();
  }
  for (int m = 0; m < 4; ++m) {
    long row0 = arow + wr * 64 + m * 16 + hi * 4;
    for (int n = 0; n < 4; ++n) {
      long col = brow + wc * 64 + n * 16 + lo;
      for (int r = 0; r < 4; ++r)
        C[(row0 + r) * (long)N + col] = acc[m][n][r];
    }
  }
}

// ---------------- flash attention: 8-wave blocks, K/V double-buffered LDS, split-K ----------------
// Round-10 structure (known-good 64us). Changes: (1) balanced XCD units -- pair chunks
// {c0,c3}/{c1,c2} into 24 units of 528 block-iters, 3 units/XCD = 1584 each (old swizzle
// was 1840 vs 1328, +-19% tail); (2) s_setprio(1) around MFMA clusters (T5).
// launch_bounds (512,4): VGPR cap 128 -- (512,6) forced VGPR=40 and spilled ~150MB/dispatch.
__global__ __launch_bounds__(512, 4) void flash_attn(const ushort* __restrict__ Q,
                                                     const ushort* __restrict__ Kb,
                                                     const ushort* __restrict__ Vt,
                                                     char* __restrict__ part) {
  const int n    = blockIdx.x;
  const int unit = (n & 7) * 3 + ((n >> 3) >> 6);  // 0..23, 3 units per XCD
  const int j    = (n >> 3) & 63;
  const int h    = (unit < 12) ? unit : unit - 12;
  const int c    = (unit < 12) ? ((j < 32) ? 0 : 3) : ((j < 32) ? 1 : 2);
  const int qb   = j & 31;                          // 128-row q-tile
  const int kstart  = c << 10;
  const int blk_lim = qb * 128 + 128;
  if (kstart >= blk_lim) return;
  const int kend = (kstart + 1024 < blk_lim) ? kstart + 1024 : blk_lim;

  __shared__ ushort Ks[2][4096];   // [64 rows][64 bf16], XOR-swizzled content
  __shared__ ushort Vs[2][4096];
  __shared__ ushort P[8][16][72];

  const int t = threadIdx.x;
  const int w = t >> 6, l = t & 63;
  const int lo = l & 15, hi = l >> 4, lo7 = l & 7;
  const int qrow0 = qb * 128 + w * 16;
  const int qlim  = qrow0 + 16;
  const int qabs  = qrow0 + lo;
  const long hT   = (long)h * T_SEQ;
  const long hT64 = (long)h * 64;

  const int srow8 = l >> 3;               // 0..7: row within this wave's 8-row group
  const int row_w = w * 8 + srow8;        // 0..63: tile row this lane stages
  const int schk  = (l & 7) ^ srow8;      // inverse-swizzled source 16B-chunk

  bf16x8 qf0, qf1;
  {
    const ushort* qp = Q + (hT + qrow0 + lo) * 64 + hi * 8;
    qf0 = *(const bf16x8*)qp;
    qf1 = *(const bf16x8*)(qp + 32);
  }
  f32x4 o[4] = {};
  float m = -1e30f, lsum = 0.0f;

#define STAGE(buf, k0s)                                                         \
  {                                                                             \
    gload_lds16(Kb + (hT + (k0s) + row_w) * 64 + schk * 8,                      \
                (char*)&Ks[buf][0] + w * 1024);                                 \
    gload_lds16(Vt + (hT64 + row_w) * T_SEQ + (k0s) + schk * 8,                 \
                (char*)&Vs[buf][0] + w * 1024);                                 \
  }

  STAGE(0, kstart);
  __syncthreads();
  int buf = 0;

  for (int k0 = kstart; k0 < kend; k0 += 64) {
    if (k0 + 64 < kend) STAGE(buf ^ 1, k0 + 64);
    if (k0 < qlim) {
      const ushort* kt_ = &Ks[buf][0];
      const ushort* vt_ = &Vs[buf][0];
      // --- S^T = K . Q^T from swizzled LDS ---
      f32x4 s[4];
      __builtin_amdgcn_s_setprio(1);
#pragma unroll
      for (int kt = 0; kt < 4; ++kt) {
        int rr = kt * 16 + lo;
        bf16x8 ka = *(const bf16x8*)(kt_ + rr * 64 + ((hi ^ lo7) * 8));
        bf16x8 kc = *(const bf16x8*)(kt_ + rr * 64 + (((4 + hi) ^ lo7) * 8));
        f32x4 a = {};
        a = __builtin_amdgcn_mfma_f32_16x16x32_bf16(ka, qf0, a, 0, 0, 0);
        a = __builtin_amdgcn_mfma_f32_16x16x32_bf16(kc, qf1, a, 0, 0, 0);
        s[kt] = a;
      }
      __builtin_amdgcn_s_setprio(0);
      // --- V fragments early (latency overlaps softmax) ---
      bf16x8 vf[8];
#pragma unroll
      for (int dt = 0; dt < 4; ++dt)
#pragma unroll
        for (int cc = 0; cc < 2; ++cc) {
          int rr = dt * 16 + lo;
          vf[dt * 2 + cc] = *(const bf16x8*)(vt_ + rr * 64 + (((cc * 4 + hi) ^ lo7) * 8));
        }
      // --- causal mask (diagonal tiles only) ---
      if (k0 + 64 > qrow0) {
#pragma unroll
        for (int kt = 0; kt < 4; ++kt)
#pragma unroll
          for (int r = 0; r < 4; ++r) {
            int key = k0 + kt * 16 + hi * 4 + r;
            if (key > qabs) s[kt][r] = -1e30f;
          }
      }
      // --- row max: 15 in-lane fmax + 2 shfl ---
      float mt = s[0][0];
#pragma unroll
      for (int kt = 0; kt < 4; ++kt)
#pragma unroll
        for (int r = 0; r < 4; ++r) mt = fmaxf(mt, s[kt][r]);
      mt = fmaxf(mt, __shfl_xor(mt, 16));
      mt = fmaxf(mt, __shfl_xor(mt, 32));
      // --- defer-max rescale (THR=8 in log2 domain) ---
      if (!__all(mt - m <= 8.0f)) {
        float mn = fmaxf(m, mt);
        float alpha = EXP2F(m - mn);
        m = mn;
        lsum *= alpha;
#pragma unroll
        for (int r = 0; r < 4; ++r) {
          float ar = __shfl(alpha, hi * 4 + r);
#pragma unroll
          for (int dt = 0; dt < 4; ++dt) o[dt][r] *= ar;
        }
      }
      // --- exp2 + per-lane sum + pack P ---
#pragma unroll
      for (int kt = 0; kt < 4; ++kt) {
        float p0 = EXP2F(s[kt][0] - m);
        float p1 = EXP2F(s[kt][1] - m);
        float p2 = EXP2F(s[kt][2] - m);
        float p3 = EXP2F(s[kt][3] - m);
        lsum += (p0 + p1) + (p2 + p3);
        uint2 pk;
        pk.x = (uint)f2b(p0) | ((uint)f2b(p1) << 16);
        pk.y = (uint)f2b(p2) | ((uint)f2b(p3) << 16);
        *(uint2*)&P[w][lo][kt * 16 + hi * 4] = pk;
      }
      asm volatile("s_waitcnt lgkmcnt(0)" ::: "memory");
      // --- PV from registers ---
      __builtin_amdgcn_s_setprio(1);
#pragma unroll
      for (int cc = 0; cc < 2; ++cc) {
        bf16x8 pa = *(const bf16x8*)&P[w][lo][cc * 32 + hi * 8];
#pragma unroll
        for (int dt = 0; dt < 4; ++dt)
          o[dt] = __builtin_amdgcn_mfma_f32_16x16x32_bf16(pa, vf[dt * 2 + cc], o[dt], 0, 0, 0);
      }
      __builtin_amdgcn_s_setprio(0);
    }
    __syncthreads();
    buf ^= 1;
  }
#undef STAGE

  // --- write partial (unnormalized); wave active iff kstart < qlim ---
  if (kstart < qlim) {
    lsum += __shfl_xor(lsum, 16);
    lsum += __shfl_xor(lsum, 32);
    const int qg = qb * 8 + w;
    char* pb = part + (((long)(h * 256 + qg)) * 4 + c) * 2176;
    ushort* po = (ushort*)pb;
#pragma unroll
    for (int dt = 0; dt < 4; ++dt)
#pragma unroll
      for (int r = 0; r < 4; ++r)
        po[(hi * 4 + r) * 64 + dt * 16 + lo] = f2b(o[dt][r]);
    if (hi == 0) {
      ((float*)(pb + 2048))[lo] = m;
      ((float*)(pb + 2112))[lo] = lsum;
    }
  }
}

// ---------------- split-K combine ----------------
__global__ __launch_bounds__(64) void flash_combine(const char* __restrict__ part,
                                                    ushort* __restrict__ Y) {
  const int qg = blockIdx.x, h = blockIdx.y, d = threadIdx.x;
  const int qrow0 = qg * 16;
  const int nch = (qrow0 + 16 + 1023) >> 10;
  const char* ub = part + ((long)(h * 256 + qg)) * 4 * 2176;
  float Mg[16];
#pragma unroll
  for (int r = 0; r < 16; ++r) Mg[r] = -1e30f;
  for (int cc = 0; cc < nch; ++cc) {
    const float* mp = (const float*)(ub + cc * 2176 + 2048);
#pragma unroll
    for (int r = 0; r < 16; ++r) Mg[r] = fmaxf(Mg[r], mp[r]);
  }
  float acc[16], lg[16];
#pragma unroll
  for (int r = 0; r < 16; ++r) { acc[r] = 0.0f; lg[r] = 0.0f; }
  for (int cc = 0; cc < nch; ++cc) {
    const ushort* op = (const ushort*)(ub + cc * 2176);
    const float* mp = (const float*)(ub + cc * 2176 + 2048);
    const float* lp = (const float*)(ub + cc * 2176 + 2112);
#pragma unroll
    for (int r = 0; r < 16; ++r) {
      float wgt = EXP2F(mp[r] - Mg[r]);
      acc[r] += wgt * b2f(op[r * 64 + d]);
      lg[r]  += wgt * lp[r];
    }
  }
#pragma unroll
  for (int r = 0; r < 16; ++r)
    Y[(long)(qrow0 + r) * 768 + h * 64 + d] = f2b(acc[r] / lg[r]);
}

extern "C" void kernel_launch(void* const* d_in, const int* in_sizes, int n_in,
                              void* d_out, int out_size, void* d_ws, size_t ws_size,
                              hipStream_t stream) {
  const float* x      = (const float*)d_in[0];
  const float* w_attn = (const float*)d_in[1];
  const float* w_proj = (const float*)d_in[2];
  float* out = (float*)d_out;
  char* ws = (char*)d_ws;

  ushort* xb   = (ushort*)(ws);                 // 4096*768
  ushort* wAb  = (ushort*)(ws + 6291456);       // 2304*768
  ushort* wPb  = (ushort*)(ws + 9830400);       // 768*768
  float*  cosT = (float*)(ws + 11010048);       // 4096*32
  float*  sinT = (float*)(ws + 11534336);
  char*   partR = (ws + 12058624);              // flash split-K partials
  ushort* Qb   = (ushort*)(ws + 49807360);      // [12][4096][64]
  ushort* Kbb  = (ushort*)(ws + 56098816);
  ushort* Vt   = (ushort*)(ws + 62390272);      // [12][64][4096]
  ushort* Yb   = (ushort*)(ws + 68681728);      // [4096][768]

  prep_all<<<2752, 256, 0, stream>>>(x, w_attn, w_proj, xb, wAb, wPb, cosT, sinT);
  gemm_qkv<<<576, 256, 0, stream>>>(xb, wAb, cosT, sinT, Qb, Kbb, Vt);
  flash_attn<<<1536, 512, 0, stream>>>(Qb, Kbb, Vt, partR);
  flash_combine<<<dim3(256, NH), 64, 0, stream>>>(partR, Yb);
  gemm_bt<<<192, 256, 0, stream>>>(Yb, wPb, out, 4096, 768, 768);
}

// Round 14
// 133.231 us; speedup vs baseline: 1.5847x; 1.0130x over previous
//
#include <hip/hip_runtime.h>
#include <hip/hip_bf16.h>
#include <stdint.h>

#define T_SEQ 4096
#define NH 12

#if __has_builtin(__builtin_amdgcn_exp2f)
#define EXP2F __builtin_amdgcn_exp2f
#else
#define EXP2F exp2f
#endif

typedef __attribute__((ext_vector_type(4))) float f32x4;
typedef __attribute__((ext_vector_type(8))) __bf16 bf16x8;

__device__ inline ushort f2b(float f) {
  __hip_bfloat16 h = __float2bfloat16(f);
  return *reinterpret_cast<ushort*>(&h);
}
__device__ inline float b2f(ushort u) {
  union { uint i; float f; } v; v.i = (uint)u << 16; return v.f;
}

__device__ inline void gload_lds16(const void* g, void* lds) {
  auto g1 = (const __attribute__((address_space(1))) uint32_t*)(uintptr_t)g;
  auto l3 = (__attribute__((address_space(3))) uint32_t*)(uintptr_t)lds;
  __builtin_amdgcn_global_load_lds(g1, l3, 16, 0, 0);
}

// ---------------- fused prep: 3x fp32->bf16 convert + RoPE tables, one launch ----------------
__global__ __launch_bounds__(256) void prep_all(const float* __restrict__ x,
                                                const float* __restrict__ wA,
                                                const float* __restrict__ wP,
                                                ushort* __restrict__ xb,
                                                ushort* __restrict__ wAb,
                                                ushort* __restrict__ wPb,
                                                float* __restrict__ cosT,
                                                float* __restrict__ sinT) {
  const int u = blockIdx.x * blockDim.x + threadIdx.x;
  if (u < 688128) {
    const float* src;
    ushort* dst;
    long i;
    if (u < 393216)      { src = x;  dst = xb;  i = u; }
    else if (u < 614400) { src = wA; dst = wAb; i = u - 393216; }
    else                 { src = wP; dst = wPb; i = u - 614400; }
    const float4* s4 = (const float4*)src;
    float4 a = s4[i * 2], b = s4[i * 2 + 1];
    uint4 o;
    o.x = (uint)f2b(a.x) | ((uint)f2b(a.y) << 16);
    o.y = (uint)f2b(a.z) | ((uint)f2b(a.w) << 16);
    o.z = (uint)f2b(b.x) | ((uint)f2b(b.y) << 16);
    o.w = (uint)f2b(b.z) | ((uint)f2b(b.w) << 16);
    *(uint4*)(dst + i * 8) = o;
  } else if (u < 704512) {
    const int base = (u - 688128) * 8;   // i = t*32 + d
    const int t = base >> 5;
#pragma unroll
    for (int j = 0; j < 8; ++j) {
      const int d = (base + j) & 31;
      float theta = 1.0f / powf(10000.0f, (float)d * (1.0f / 32.0f));
      float a = (float)t * theta;
      cosT[base + j] = cosf(a);
      sinT[base + j] = sinf(a);
    }
  }
}

// ---------------- GEMM1 + fused RoPE/reorder epilogue (1D grid, XCD-swizzled) ----------------
__global__ __launch_bounds__(256) void gemm_qkv(const ushort* __restrict__ A,
                                                const ushort* __restrict__ B,
                                                const float* __restrict__ cosT,
                                                const float* __restrict__ sinT,
                                                ushort* __restrict__ Q,
                                                ushort* __restrict__ Kb,
                                                ushort* __restrict__ Vt) {
  __shared__ ushort As[128 * 64];
  __shared__ ushort Bs[128 * 64];
  const int wg = (blockIdx.x & 7) * 72 + (blockIdx.x >> 3);
  const int bx = wg % 18;
  const int by = wg / 18;
  const int t = threadIdx.x;
  const int w = t >> 6, l = t & 63;
  const int lo = l & 15, hi = l >> 4;
  const int wr = w >> 1, wc = w & 1;
  const long arow = (long)by * 128;
  const long brow = (long)bx * 128;
  const int K = 768;
  f32x4 acc[4][4] = {};
  for (int k0 = 0; k0 < K; k0 += 64) {
    for (int i = 0; i < 4; ++i) {
      int e = i * 2048 + t * 8;
      int r = e >> 6, c = e & 63;
      const ushort* ga = A + (arow + r) * (long)K + k0 + c;
      const ushort* gb = B + (brow + r) * (long)K + k0 + c;
      uint32_t ldsoff = i * 4096 + w * 1024;
      gload_lds16(ga, (char*)As + ldsoff);
      gload_lds16(gb, (char*)Bs + ldsoff);
    }
    __syncthreads();
    for (int kk = 0; kk < 2; ++kk) {
      bf16x8 af[4], bfr[4];
      for (int m = 0; m < 4; ++m)
        af[m] = *(const bf16x8*)&As[(wr * 64 + m * 16 + lo) * 64 + kk * 32 + hi * 8];
      for (int n = 0; n < 4; ++n)
        bfr[n] = *(const bf16x8*)&Bs[(wc * 64 + n * 16 + lo) * 64 + kk * 32 + hi * 8];
      for (int m = 0; m < 4; ++m)
        for (int n = 0; n < 4; ++n)
          acc[m][n] = __builtin_amdgcn_mfma_f32_16x16x32_bf16(af[m], bfr[n], acc[m][n], 0, 0, 0);
    }
    __syncthreads();
  }
  // ---- fused epilogue ----
  const int rq = bx / 6;                 // 0=Q, 1=K, 2=V
  const int h  = (bx % 6) * 2 + wc;      // head for this thread's cols
  const long hT = (long)h * T_SEQ;
  if (rq < 2) {
    ushort* dst = (rq == 0) ? Q : Kb;
    const float qsc = (rq == 0) ? 0.125f * 1.44269504f : 1.0f;
#pragma unroll
    for (int m = 0; m < 4; ++m)
#pragma unroll
      for (int r = 0; r < 4; ++r) {
        const long trow = arow + wr * 64 + m * 16 + hi * 4 + r;
        ushort* rowp = dst + (hT + trow) * 64;
        const float* cp = cosT + trow * 32;
        const float* sp = sinT + trow * 32;
#pragma unroll
        for (int n = 0; n < 2; ++n) {
          const int dd = n * 16 + lo;
          const float cs = cp[dd], sn = sp[dd];
          const float a = acc[m][n][r], b = acc[m][n + 2][r];
          rowp[dd]      = f2b((a * cs - b * sn) * qsc);
          rowp[dd + 32] = f2b((a * sn + b * cs) * qsc);
        }
      }
  } else {
#pragma unroll
    for (int m = 0; m < 4; ++m) {
      const long trow0 = arow + wr * 64 + m * 16 + hi * 4;
#pragma unroll
      for (int n = 0; n < 4; ++n) {
        const int d = n * 16 + lo;
        uint2 pk;
        pk.x = (uint)f2b(acc[m][n][0]) | ((uint)f2b(acc[m][n][1]) << 16);
        pk.y = (uint)f2b(acc[m][n][2]) | ((uint)f2b(acc[m][n][3]) << 16);
        *(uint2*)(Vt + ((long)h * 64 + d) * T_SEQ + trow0) = pk;
      }
    }
  }
}

// ---------------- bf16 GEMM, C = A * B^T (fp32 out; out-proj; 1D grid, XCD-swizzled) ----------------
__global__ __launch_bounds__(256) void gemm_bt(const ushort* __restrict__ A,
                                               const ushort* __restrict__ B,
                                               float* __restrict__ C,
                                               int M, int N, int K) {
  __shared__ ushort As[128 * 64];
  __shared__ ushort Bs[128 * 64];
  const int nbx = N >> 7;
  const int nwg = (M >> 7) * nbx;
  const int cpx = nwg >> 3;
  const int wg = (blockIdx.x & 7) * cpx + (blockIdx.x >> 3);
  const int bx = wg % nbx;
  const int by = wg / nbx;
  const int t = threadIdx.x;
  const int w = t >> 6, l = t & 63;
  const int lo = l & 15, hi = l >> 4;
  const int wr = w >> 1, wc = w & 1;
  const long arow = (long)by * 128;
  const long brow = (long)bx * 128;
  f32x4 acc[4][4] = {};
  for (int k0 = 0; k0 < K; k0 += 64) {
    for (int i = 0; i < 4; ++i) {
      int e = i * 2048 + t * 8;
      int r = e >> 6, c = e & 63;
      const ushort* ga = A + (arow + r) * (long)K + k0 + c;
      const ushort* gb = B + (brow + r) * (long)K + k0 + c;
      uint32_t ldsoff = i * 4096 + w * 1024;
      gload_lds16(ga, (char*)As + ldsoff);
      gload_lds16(gb, (char*)Bs + ldsoff);
    }
    __syncthreads();
    for (int kk = 0; kk < 2; ++kk) {
      bf16x8 af[4], bfr[4];
      for (int m = 0; m < 4; ++m)
        af[m] = *(const bf16x8*)&As[(wr * 64 + m * 16 + lo) * 64 + kk * 32 + hi * 8];
      for (int n = 0; n < 4; ++n)
        bfr[n] = *(const bf16x8*)&Bs[(wc * 64 + n * 16 + lo) * 64 + kk * 32 + hi * 8];
      for (int m = 0; m < 4; ++m)
        for (int n = 0; n < 4; ++n)
          acc[m][n] = __builtin_amdgcn_mfma_f32_16x16x32_bf16(af[m], bfr[n], acc[m][n], 0, 0, 0);
    }
    __syncthreads();
  }
  for (int m = 0; m < 4; ++m) {
    long row0 = arow + wr * 64 + m * 16 + hi * 4;
    for (int n = 0; n < 4; ++n) {
      long col = brow + wc * 64 + n * 16 + lo;
      for (int r = 0; r < 4; ++r)
        C[(row0 + r) * (long)N + col] = acc[m][n][r];
    }
  }
}

// ---------------- flash attention: 8-wave blocks, permuted-K staging, NO P-LDS bounce ----------------
// K rows are staged PERMUTED: LDS tile-row rho holds K key pi(rho),
//   pi(rho) = 32*((rho>>5)&1) + 8*((rho>>2)&3) + 4*((rho>>4)&1) + (rho&3).
// With swapped QK^T this makes each lane's 16 softmax values exactly its PV
// A-fragment in register order (pa[cc] = {u[2cc],u[2cc+1]}) -- the P LDS bounce,
// its lgkmcnt(0) drain, and 18KB of LDS are all deleted. LDS 32KB -> 4 blocks/CU.
// Causal mask key for s[kt][r]: k0 + (kt>>1)*32 + (kt&1)*4 + hi*8 + r.
// launch_bounds (512,4): VGPR cap 128 -- (512,6) forced VGPR=40 and spilled ~150MB/dispatch.
__global__ __launch_bounds__(512, 4) void flash_attn(const ushort* __restrict__ Q,
                                                     const ushort* __restrict__ Kb,
                                                     const ushort* __restrict__ Vt,
                                                     char* __restrict__ part) {
  const int n    = blockIdx.x;
  const int unit = (n & 7) * 3 + ((n >> 3) >> 6);  // 0..23, 3 units per XCD
  const int j    = (n >> 3) & 63;
  const int h    = (unit < 12) ? unit : unit - 12;
  const int c    = (unit < 12) ? ((j < 32) ? 0 : 3) : ((j < 32) ? 1 : 2);
  const int qb   = j & 31;                          // 128-row q-tile
  const int kstart  = c << 10;
  const int blk_lim = qb * 128 + 128;
  if (kstart >= blk_lim) return;
  const int kend = (kstart + 1024 < blk_lim) ? kstart + 1024 : blk_lim;

  __shared__ ushort Ks[2][4096];   // [64 rows][64 bf16], rows key-permuted, chunks XOR-swizzled
  __shared__ ushort Vs[2][4096];

  const int t = threadIdx.x;
  const int w = t >> 6, l = t & 63;
  const int lo = l & 15, hi = l >> 4, lo7 = l & 7;
  const int qrow0 = qb * 128 + w * 16;
  const int qlim  = qrow0 + 16;
  const int qabs  = qrow0 + lo;
  const long hT   = (long)h * T_SEQ;
  const long hT64 = (long)h * 64;

  const int srow8 = l >> 3;               // 0..7: row within this wave's 8-row group
  const int row_w = w * 8 + srow8;        // 0..63: LDS tile row this lane stages
  const int prow  = ((row_w >> 5) & 1) * 32 + ((row_w >> 2) & 3) * 8 +
                    ((row_w >> 4) & 1) * 4 + (row_w & 3);   // pi(row_w): source K key
  const int schk  = (l & 7) ^ srow8;      // inverse-swizzled source 16B-chunk

  bf16x8 qf0, qf1;
  {
    const ushort* qp = Q + (hT + qrow0 + lo) * 64 + hi * 8;
    qf0 = *(const bf16x8*)qp;
    qf1 = *(const bf16x8*)(qp + 32);
  }
  f32x4 o[4] = {};
  float m = -1e30f, lsum = 0.0f;

#define STAGE(buf, k0s)                                                         \
  {                                                                             \
    gload_lds16(Kb + (hT + (k0s) + prow) * 64 + schk * 8,                       \
                (char*)&Ks[buf][0] + w * 1024);                                 \
    gload_lds16(Vt + (hT64 + row_w) * T_SEQ + (k0s) + schk * 8,                 \
                (char*)&Vs[buf][0] + w * 1024);                                 \
  }

  STAGE(0, kstart);
  __syncthreads();
  int buf = 0;

  for (int k0 = kstart; k0 < kend; k0 += 64) {
    if (k0 + 64 < kend) STAGE(buf ^ 1, k0 + 64);
    if (k0 < qlim) {
      const ushort* kt_ = &Ks[buf][0];
      const ushort* vt_ = &Vs[buf][0];
      // --- S^T = K . Q^T from swizzled LDS (rows key-permuted) ---
      f32x4 s[4];
      __builtin_amdgcn_s_setprio(1);
#pragma unroll
      for (int kt = 0; kt < 4; ++kt) {
        int rr = kt * 16 + lo;
        bf16x8 ka = *(const bf16x8*)(kt_ + rr * 64 + ((hi ^ lo7) * 8));
        bf16x8 kc = *(const bf16x8*)(kt_ + rr * 64 + (((4 + hi) ^ lo7) * 8));
        f32x4 a = {};
        a = __builtin_amdgcn_mfma_f32_16x16x32_bf16(ka, qf0, a, 0, 0, 0);
        a = __builtin_amdgcn_mfma_f32_16x16x32_bf16(kc, qf1, a, 0, 0, 0);
        s[kt] = a;
      }
      __builtin_amdgcn_s_setprio(0);
      // --- V fragments early (latency overlaps softmax) ---
      bf16x8 vf[8];
#pragma unroll
      for (int dt = 0; dt < 4; ++dt)
#pragma unroll
        for (int cc = 0; cc < 2; ++cc) {
          int rr = dt * 16 + lo;
          vf[dt * 2 + cc] = *(const bf16x8*)(vt_ + rr * 64 + (((cc * 4 + hi) ^ lo7) * 8));
        }
      // --- causal mask (diagonal tiles only); key honors the row permutation ---
      if (k0 + 64 > qrow0) {
#pragma unroll
        for (int kt = 0; kt < 4; ++kt) {
          const int bkt = (kt >> 1) * 32 + (kt & 1) * 4;
#pragma unroll
          for (int r = 0; r < 4; ++r) {
            int key = k0 + bkt + hi * 8 + r;
            if (key > qabs) s[kt][r] = -1e30f;
          }
        }
      }
      // --- row max: 15 in-lane fmax + 2 shfl ---
      float mt = s[0][0];
#pragma unroll
      for (int kt = 0; kt < 4; ++kt)
#pragma unroll
        for (int r = 0; r < 4; ++r) mt = fmaxf(mt, s[kt][r]);
      mt = fmaxf(mt, __shfl_xor(mt, 16));
      mt = fmaxf(mt, __shfl_xor(mt, 32));
      // --- defer-max rescale (THR=8 in log2 domain) ---
      if (!__all(mt - m <= 8.0f)) {
        float mn = fmaxf(m, mt);
        float alpha = EXP2F(m - mn);
        m = mn;
        lsum *= alpha;
#pragma unroll
        for (int r = 0; r < 4; ++r) {
          float ar = __shfl(alpha, hi * 4 + r);
#pragma unroll
          for (int dt = 0; dt < 4; ++dt) o[dt][r] *= ar;
        }
      }
      // --- exp2 + per-lane sum + pack P into registers (no LDS!) ---
      uint us[8];
#pragma unroll
      for (int kt = 0; kt < 4; ++kt) {
        float p0 = EXP2F(s[kt][0] - m);
        float p1 = EXP2F(s[kt][1] - m);
        float p2 = EXP2F(s[kt][2] - m);
        float p3 = EXP2F(s[kt][3] - m);
        lsum += (p0 + p1) + (p2 + p3);
        us[kt * 2]     = (uint)f2b(p0) | ((uint)f2b(p1) << 16);
        us[kt * 2 + 1] = (uint)f2b(p2) | ((uint)f2b(p3) << 16);
      }
      // --- PV: A-fragment is a pure register reassembly ---
      __builtin_amdgcn_s_setprio(1);
#pragma unroll
      for (int cc = 0; cc < 2; ++cc) {
        union { uint4 q; bf16x8 v; } pc;
        pc.q.x = us[cc * 4 + 0];
        pc.q.y = us[cc * 4 + 1];
        pc.q.z = us[cc * 4 + 2];
        pc.q.w = us[cc * 4 + 3];
#pragma unroll
        for (int dt = 0; dt < 4; ++dt)
          o[dt] = __builtin_amdgcn_mfma_f32_16x16x32_bf16(pc.v, vf[dt * 2 + cc], o[dt], 0, 0, 0);
      }
      __builtin_amdgcn_s_setprio(0);
    }
    __syncthreads();
    buf ^= 1;
  }
#undef STAGE

  // --- write partial (unnormalized); wave active iff kstart < qlim ---
  if (kstart < qlim) {
    lsum += __shfl_xor(lsum, 16);
    lsum += __shfl_xor(lsum, 32);
    const int qg = qb * 8 + w;
    char* pb = part + (((long)(h * 256 + qg)) * 4 + c) * 2176;
    ushort* po = (ushort*)pb;
#pragma unroll
    for (int dt = 0; dt < 4; ++dt)
#pragma unroll
      for (int r = 0; r < 4; ++r)
        po[(hi * 4 + r) * 64 + dt * 16 + lo] = f2b(o[dt][r]);
    if (hi == 0) {
      ((float*)(pb + 2048))[lo] = m;
      ((float*)(pb + 2112))[lo] = lsum;
    }
  }
}

// ---------------- split-K combine ----------------
__global__ __launch_bounds__(64) void flash_combine(const char* __restrict__ part,
                                                    ushort* __restrict__ Y) {
  const int qg = blockIdx.x, h = blockIdx.y, d = threadIdx.x;
  const int qrow0 = qg * 16;
  const int nch = (qrow0 + 16 + 1023) >> 10;
  const char* ub = part + ((long)(h * 256 + qg)) * 4 * 2176;
  float Mg[16];
#pragma unroll
  for (int r = 0; r < 16; ++r) Mg[r] = -1e30f;
  for (int cc = 0; cc < nch; ++cc) {
    const float* mp = (const float*)(ub + cc * 2176 + 2048);
#pragma unroll
    for (int r = 0; r < 16; ++r) Mg[r] = fmaxf(Mg[r], mp[r]);
  }
  float acc[16], lg[16];
#pragma unroll
  for (int r = 0; r < 16; ++r) { acc[r] = 0.0f; lg[r] = 0.0f; }
  for (int cc = 0; cc < nch; ++cc) {
    const ushort* op = (const ushort*)(ub + cc * 2176);
    const float* mp = (const float*)(ub + cc * 2176 + 2048);
    const float* lp = (const float*)(ub + cc * 2176 + 2112);
#pragma unroll
    for (int r = 0; r < 16; ++r) {
      float wgt = EXP2F(mp[r] - Mg[r]);
      acc[r] += wgt * b2f(op[r * 64 + d]);
      lg[r]  += wgt * lp[r];
    }
  }
#pragma unroll
  for (int r = 0; r < 16; ++r)
    Y[(long)(qrow0 + r) * 768 + h * 64 + d] = f2b(acc[r] / lg[r]);
}

extern "C" void kernel_launch(void* const* d_in, const int* in_sizes, int n_in,
                              void* d_out, int out_size, void* d_ws, size_t ws_size,
                              hipStream_t stream) {
  const float* x      = (const float*)d_in[0];
  const float* w_attn = (const float*)d_in[1];
  const float* w_proj = (const float*)d_in[2];
  float* out = (float*)d_out;
  char* ws = (char*)d_ws;

  ushort* xb   = (ushort*)(ws);                 // 4096*768
  ushort* wAb  = (ushort*)(ws + 6291456);       // 2304*768
  ushort* wPb  = (ushort*)(ws + 9830400);       // 768*768
  float*  cosT = (float*)(ws + 11010048);       // 4096*32
  float*  sinT = (float*)(ws + 11534336);
  char*   partR = (ws + 12058624);              // flash split-K partials
  ushort* Qb   = (ushort*)(ws + 49807360);      // [12][4096][64]
  ushort* Kbb  = (ushort*)(ws + 56098816);
  ushort* Vt   = (ushort*)(ws + 62390272);      // [12][64][4096]
  ushort* Yb   = (ushort*)(ws + 68681728);      // [4096][768]

  prep_all<<<2752, 256, 0, stream>>>(x, w_attn, w_proj, xb, wAb, wPb, cosT, sinT);
  gemm_qkv<<<576, 256, 0, stream>>>(xb, wAb, cosT, sinT, Qb, Kbb, Vt);
  flash_attn<<<1536, 512, 0, stream>>>(Qb, Kbb, Vt, partR);
  flash_combine<<<dim3(256, NH), 64, 0, stream>>>(partR, Yb);
  gemm_bt<<<192, 256, 0, stream>>>(Yb, wPb, out, 4096, 768, 768);
}

// Round 15
// 132.917 us; speedup vs baseline: 1.5885x; 1.0024x over previous
//
#include <hip/hip_runtime.h>
#include <hip/hip_bf16.h>
#include <stdint.h>

#define T_SEQ 4096
#define NH 12

#if __has_builtin(__builtin_amdgcn_exp2f)
#define EXP2F __builtin_amdgcn_exp2f
#else
#define EXP2F exp2f
#endif

typedef __attribute__((ext_vector_type(4))) float f32x4;
typedef __attribute__((ext_vector_type(8))) __bf16 bf16x8;

__device__ inline ushort f2b(float f) {
  __hip_bfloat16 h = __float2bfloat16(f);
  return *reinterpret_cast<ushort*>(&h);
}
__device__ inline float b2f(ushort u) {
  union { uint i; float f; } v; v.i = (uint)u << 16; return v.f;
}

__device__ inline void gload_lds16(const void* g, void* lds) {
  auto g1 = (const __attribute__((address_space(1))) uint32_t*)(uintptr_t)g;
  auto l3 = (__attribute__((address_space(3))) uint32_t*)(uintptr_t)lds;
  __builtin_amdgcn_global_load_lds(g1, l3, 16, 0, 0);
}

// ---------------- fused prep: 3x fp32->bf16 convert + RoPE tables, one launch ----------------
__global__ __launch_bounds__(256) void prep_all(const float* __restrict__ x,
                                                const float* __restrict__ wA,
                                                const float* __restrict__ wP,
                                                ushort* __restrict__ xb,
                                                ushort* __restrict__ wAb,
                                                ushort* __restrict__ wPb,
                                                float* __restrict__ cosT,
                                                float* __restrict__ sinT) {
  const int u = blockIdx.x * blockDim.x + threadIdx.x;
  if (u < 688128) {
    const float* src;
    ushort* dst;
    long i;
    if (u < 393216)      { src = x;  dst = xb;  i = u; }
    else if (u < 614400) { src = wA; dst = wAb; i = u - 393216; }
    else                 { src = wP; dst = wPb; i = u - 614400; }
    const float4* s4 = (const float4*)src;
    float4 a = s4[i * 2], b = s4[i * 2 + 1];
    uint4 o;
    o.x = (uint)f2b(a.x) | ((uint)f2b(a.y) << 16);
    o.y = (uint)f2b(a.z) | ((uint)f2b(a.w) << 16);
    o.z = (uint)f2b(b.x) | ((uint)f2b(b.y) << 16);
    o.w = (uint)f2b(b.z) | ((uint)f2b(b.w) << 16);
    *(uint4*)(dst + i * 8) = o;
  } else if (u < 704512) {
    const int base = (u - 688128) * 8;   // i = t*32 + d
    const int t = base >> 5;
#pragma unroll
    for (int j = 0; j < 8; ++j) {
      const int d = (base + j) & 31;
      float theta = 1.0f / powf(10000.0f, (float)d * (1.0f / 32.0f));
      float a = (float)t * theta;
      cosT[base + j] = cosf(a);
      sinT[base + j] = sinf(a);
    }
  }
}

// ---------------- GEMM1 + fused RoPE/reorder epilogue (1D grid, XCD-swizzled) ----------------
__global__ __launch_bounds__(256) void gemm_qkv(const ushort* __restrict__ A,
                                                const ushort* __restrict__ B,
                                                const float* __restrict__ cosT,
                                                const float* __restrict__ sinT,
                                                ushort* __restrict__ Q,
                                                ushort* __restrict__ Kb,
                                                ushort* __restrict__ Vt) {
  __shared__ ushort As[128 * 64];
  __shared__ ushort Bs[128 * 64];
  const int wg = (blockIdx.x & 7) * 72 + (blockIdx.x >> 3);
  const int bx = wg % 18;
  const int by = wg / 18;
  const int t = threadIdx.x;
  const int w = t >> 6, l = t & 63;
  const int lo = l & 15, hi = l >> 4;
  const int wr = w >> 1, wc = w & 1;
  const long arow = (long)by * 128;
  const long brow = (long)bx * 128;
  const int K = 768;
  f32x4 acc[4][4] = {};
  for (int k0 = 0; k0 < K; k0 += 64) {
    for (int i = 0; i < 4; ++i) {
      int e = i * 2048 + t * 8;
      int r = e >> 6, c = e & 63;
      const ushort* ga = A + (arow + r) * (long)K + k0 + c;
      const ushort* gb = B + (brow + r) * (long)K + k0 + c;
      uint32_t ldsoff = i * 4096 + w * 1024;
      gload_lds16(ga, (char*)As + ldsoff);
      gload_lds16(gb, (char*)Bs + ldsoff);
    }
    __syncthreads();
    for (int kk = 0; kk < 2; ++kk) {
      bf16x8 af[4], bfr[4];
      for (int m = 0; m < 4; ++m)
        af[m] = *(const bf16x8*)&As[(wr * 64 + m * 16 + lo) * 64 + kk * 32 + hi * 8];
      for (int n = 0; n < 4; ++n)
        bfr[n] = *(const bf16x8*)&Bs[(wc * 64 + n * 16 + lo) * 64 + kk * 32 + hi * 8];
      for (int m = 0; m < 4; ++m)
        for (int n = 0; n < 4; ++n)
          acc[m][n] = __builtin_amdgcn_mfma_f32_16x16x32_bf16(af[m], bfr[n], acc[m][n], 0, 0, 0);
    }
    __syncthreads();
  }
  // ---- fused epilogue ----
  const int rq = bx / 6;                 // 0=Q, 1=K, 2=V
  const int h  = (bx % 6) * 2 + wc;      // head for this thread's cols
  const long hT = (long)h * T_SEQ;
  if (rq < 2) {
    ushort* dst = (rq == 0) ? Q : Kb;
    const float qsc = (rq == 0) ? 0.125f * 1.44269504f : 1.0f;
#pragma unroll
    for (int m = 0; m < 4; ++m)
#pragma unroll
      for (int r = 0; r < 4; ++r) {
        const long trow = arow + wr * 64 + m * 16 + hi * 4 + r;
        ushort* rowp = dst + (hT + trow) * 64;
        const float* cp = cosT + trow * 32;
        const float* sp = sinT + trow * 32;
#pragma unroll
        for (int n = 0; n < 2; ++n) {
          const int dd = n * 16 + lo;
          const float cs = cp[dd], sn = sp[dd];
          const float a = acc[m][n][r], b = acc[m][n + 2][r];
          rowp[dd]      = f2b((a * cs - b * sn) * qsc);
          rowp[dd + 32] = f2b((a * sn + b * cs) * qsc);
        }
      }
  } else {
#pragma unroll
    for (int m = 0; m < 4; ++m) {
      const long trow0 = arow + wr * 64 + m * 16 + hi * 4;
#pragma unroll
      for (int n = 0; n < 4; ++n) {
        const int d = n * 16 + lo;
        uint2 pk;
        pk.x = (uint)f2b(acc[m][n][0]) | ((uint)f2b(acc[m][n][1]) << 16);
        pk.y = (uint)f2b(acc[m][n][2]) | ((uint)f2b(acc[m][n][3]) << 16);
        *(uint2*)(Vt + ((long)h * 64 + d) * T_SEQ + trow0) = pk;
      }
    }
  }
}

// ---------------- bf16 GEMM, C = A * B^T (fp32 out; out-proj; 1D grid, XCD-swizzled) ----------------
__global__ __launch_bounds__(256) void gemm_bt(const ushort* __restrict__ A,
                                               const ushort* __restrict__ B,
                                               float* __restrict__ C,
                                               int M, int N, int K) {
  __shared__ ushort As[128 * 64];
  __shared__ ushort Bs[128 * 64];
  const int nbx = N >> 7;
  const int nwg = (M >> 7) * nbx;
  const int cpx = nwg >> 3;
  const int wg = (blockIdx.x & 7) * cpx + (blockIdx.x >> 3);
  const int bx = wg % nbx;
  const int by = wg / nbx;
  const int t = threadIdx.x;
  const int w = t >> 6, l = t & 63;
  const int lo = l & 15, hi = l >> 4;
  const int wr = w >> 1, wc = w & 1;
  const long arow = (long)by * 128;
  const long brow = (long)bx * 128;
  f32x4 acc[4][4] = {};
  for (int k0 = 0; k0 < K; k0 += 64) {
    for (int i = 0; i < 4; ++i) {
      int e = i * 2048 + t * 8;
      int r = e >> 6, c = e & 63;
      const ushort* ga = A + (arow + r) * (long)K + k0 + c;
      const ushort* gb = B + (brow + r) * (long)K + k0 + c;
      uint32_t ldsoff = i * 4096 + w * 1024;
      gload_lds16(ga, (char*)As + ldsoff);
      gload_lds16(gb, (char*)Bs + ldsoff);
    }
    __syncthreads();
    for (int kk = 0; kk < 2; ++kk) {
      bf16x8 af[4], bfr[4];
      for (int m = 0; m < 4; ++m)
        af[m] = *(const bf16x8*)&As[(wr * 64 + m * 16 + lo) * 64 + kk * 32 + hi * 8];
      for (int n = 0; n < 4; ++n)
        bfr[n] = *(const bf16x8*)&Bs[(wc * 64 + n * 16 + lo) * 64 + kk * 32 + hi * 8];
      for (int m = 0; m < 4; ++m)
        for (int n = 0; n < 4; ++n)
          acc[m][n] = __builtin_amdgcn_mfma_f32_16x16x32_bf16(af[m], bfr[n], acc[m][n], 0, 0, 0);
    }
    __syncthreads();
  }
  for (int m = 0; m < 4; ++m) {
    long row0 = arow + wr * 64 + m * 16 + hi * 4;
    for (int n = 0; n < 4; ++n) {
      long col = brow + wc * 64 + n * 16 + lo;
      for (int r = 0; r < 4; ++r)
        C[(row0 + r) * (long)N + col] = acc[m][n][r];
    }
  }
}

// ---------------- flash attention: 8-wave blocks, permuted-K staging, no P-LDS bounce ----------------
// Grid = 960 ACTIVE blocks only (empties removed), LPT-ordered: within each unit the
// longest (16-iter) blocks dispatch first, 2-iter blocks backfill the tail. Each unit has
// exactly 40 active blocks (c0:32 + c3:8, or c1:24 + c2:16); 3 units/XCD = 1584 iters each.
// K rows staged PERMUTED (pi) so each lane's softmax outputs ARE its PV A-fragment
// in register order -- no P LDS bounce. Causal key: k0 + (kt>>1)*32 + (kt&1)*4 + hi*8 + r.
// launch_bounds (512,4): VGPR cap 128 -- (512,6) forced VGPR=40 and spilled ~150MB/dispatch.
__global__ __launch_bounds__(512, 4) void flash_attn(const ushort* __restrict__ Q,
                                                     const ushort* __restrict__ Kb,
                                                     const ushort* __restrict__ Vt,
                                                     char* __restrict__ part) {
  const int n    = blockIdx.x;
  const int g    = (n >> 3) / 40;                   // unit slot within XCD (0..2)
  const int i    = (n >> 3) % 40;                   // LPT index within unit
  const int unit = (n & 7) * 3 + g;                 // 0..23
  int h, c, qb;
  if (unit < 12) { h = unit;      c = (i < 32) ? 0 : 3; qb = (i < 32) ? 31 - i : 31 - (i - 32); }
  else           { h = unit - 12; c = (i < 24) ? 1 : 2; qb = (i < 24) ? 31 - i : 31 - (i - 24); }
  const int kstart  = c << 10;
  const int blk_lim = qb * 128 + 128;
  if (kstart >= blk_lim) return;                    // never taken (all blocks active)
  const int kend = (kstart + 1024 < blk_lim) ? kstart + 1024 : blk_lim;

  __shared__ ushort Ks[2][4096];   // [64 rows][64 bf16], rows key-permuted, chunks XOR-swizzled
  __shared__ ushort Vs[2][4096];

  const int t = threadIdx.x;
  const int w = t >> 6, l = t & 63;
  const int lo = l & 15, hi = l >> 4, lo7 = l & 7;
  const int qrow0 = qb * 128 + w * 16;
  const int qlim  = qrow0 + 16;
  const int qabs  = qrow0 + lo;
  const long hT   = (long)h * T_SEQ;
  const long hT64 = (long)h * 64;

  const int srow8 = l >> 3;               // 0..7: row within this wave's 8-row group
  const int row_w = w * 8 + srow8;        // 0..63: LDS tile row this lane stages
  const int prow  = ((row_w >> 5) & 1) * 32 + ((row_w >> 2) & 3) * 8 +
                    ((row_w >> 4) & 1) * 4 + (row_w & 3);   // pi(row_w): source K key
  const int schk  = (l & 7) ^ srow8;      // inverse-swizzled source 16B-chunk

  bf16x8 qf0, qf1;
  {
    const ushort* qp = Q + (hT + qrow0 + lo) * 64 + hi * 8;
    qf0 = *(const bf16x8*)qp;
    qf1 = *(const bf16x8*)(qp + 32);
  }
  f32x4 o[4] = {};
  float m = -1e30f, lsum = 0.0f;

#define STAGE(buf, k0s)                                                         \
  {                                                                             \
    gload_lds16(Kb + (hT + (k0s) + prow) * 64 + schk * 8,                       \
                (char*)&Ks[buf][0] + w * 1024);                                 \
    gload_lds16(Vt + (hT64 + row_w) * T_SEQ + (k0s) + schk * 8,                 \
                (char*)&Vs[buf][0] + w * 1024);                                 \
  }

  STAGE(0, kstart);
  __syncthreads();
  int buf = 0;

  for (int k0 = kstart; k0 < kend; k0 += 64) {
    if (k0 + 64 < kend) STAGE(buf ^ 1, k0 + 64);
    if (k0 < qlim) {
      const ushort* kt_ = &Ks[buf][0];
      const ushort* vt_ = &Vs[buf][0];
      // --- S^T = K . Q^T from swizzled LDS (rows key-permuted) ---
      f32x4 s[4];
      __builtin_amdgcn_s_setprio(1);
#pragma unroll
      for (int kt = 0; kt < 4; ++kt) {
        int rr = kt * 16 + lo;
        bf16x8 ka = *(const bf16x8*)(kt_ + rr * 64 + ((hi ^ lo7) * 8));
        bf16x8 kc = *(const bf16x8*)(kt_ + rr * 64 + (((4 + hi) ^ lo7) * 8));
        f32x4 a = {};
        a = __builtin_amdgcn_mfma_f32_16x16x32_bf16(ka, qf0, a, 0, 0, 0);
        a = __builtin_amdgcn_mfma_f32_16x16x32_bf16(kc, qf1, a, 0, 0, 0);
        s[kt] = a;
      }
      __builtin_amdgcn_s_setprio(0);
      // --- V fragments early (latency overlaps softmax) ---
      bf16x8 vf[8];
#pragma unroll
      for (int dt = 0; dt < 4; ++dt)
#pragma unroll
        for (int cc = 0; cc < 2; ++cc) {
          int rr = dt * 16 + lo;
          vf[dt * 2 + cc] = *(const bf16x8*)(vt_ + rr * 64 + (((cc * 4 + hi) ^ lo7) * 8));
        }
      // --- causal mask (diagonal tiles only); key honors the row permutation ---
      if (k0 + 64 > qrow0) {
#pragma unroll
        for (int kt = 0; kt < 4; ++kt) {
          const int bkt = (kt >> 1) * 32 + (kt & 1) * 4;
#pragma unroll
          for (int r = 0; r < 4; ++r) {
            int key = k0 + bkt + hi * 8 + r;
            if (key > qabs) s[kt][r] = -1e30f;
          }
        }
      }
      // --- row max: 15 in-lane fmax + 2 shfl ---
      float mt = s[0][0];
#pragma unroll
      for (int kt = 0; kt < 4; ++kt)
#pragma unroll
        for (int r = 0; r < 4; ++r) mt = fmaxf(mt, s[kt][r]);
      mt = fmaxf(mt, __shfl_xor(mt, 16));
      mt = fmaxf(mt, __shfl_xor(mt, 32));
      // --- defer-max rescale (THR=8 in log2 domain) ---
      if (!__all(mt - m <= 8.0f)) {
        float mn = fmaxf(m, mt);
        float alpha = EXP2F(m - mn);
        m = mn;
        lsum *= alpha;
#pragma unroll
        for (int r = 0; r < 4; ++r) {
          float ar = __shfl(alpha, hi * 4 + r);
#pragma unroll
          for (int dt = 0; dt < 4; ++dt) o[dt][r] *= ar;
        }
      }
      // --- exp2 + per-lane sum + pack P into registers (no LDS!) ---
      uint us[8];
#pragma unroll
      for (int kt = 0; kt < 4; ++kt) {
        float p0 = EXP2F(s[kt][0] - m);
        float p1 = EXP2F(s[kt][1] - m);
        float p2 = EXP2F(s[kt][2] - m);
        float p3 = EXP2F(s[kt][3] - m);
        lsum += (p0 + p1) + (p2 + p3);
        us[kt * 2]     = (uint)f2b(p0) | ((uint)f2b(p1) << 16);
        us[kt * 2 + 1] = (uint)f2b(p2) | ((uint)f2b(p3) << 16);
      }
      // --- PV: A-fragment is a pure register reassembly ---
      __builtin_amdgcn_s_setprio(1);
#pragma unroll
      for (int cc = 0; cc < 2; ++cc) {
        union { uint4 q; bf16x8 v; } pc;
        pc.q.x = us[cc * 4 + 0];
        pc.q.y = us[cc * 4 + 1];
        pc.q.z = us[cc * 4 + 2];
        pc.q.w = us[cc * 4 + 3];
#pragma unroll
        for (int dt = 0; dt < 4; ++dt)
          o[dt] = __builtin_amdgcn_mfma_f32_16x16x32_bf16(pc.v, vf[dt * 2 + cc], o[dt], 0, 0, 0);
      }
      __builtin_amdgcn_s_setprio(0);
    }
    __syncthreads();
    buf ^= 1;
  }
#undef STAGE

  // --- write partial (unnormalized); wave active iff kstart < qlim ---
  if (kstart < qlim) {
    lsum += __shfl_xor(lsum, 16);
    lsum += __shfl_xor(lsum, 32);
    const int qg = qb * 8 + w;
    char* pb = part + (((long)(h * 256 + qg)) * 4 + c) * 2176;
    ushort* po = (ushort*)pb;
#pragma unroll
    for (int dt = 0; dt < 4; ++dt)
#pragma unroll
      for (int r = 0; r < 4; ++r)
        po[(hi * 4 + r) * 64 + dt * 16 + lo] = f2b(o[dt][r]);
    if (hi == 0) {
      ((float*)(pb + 2048))[lo] = m;
      ((float*)(pb + 2112))[lo] = lsum;
    }
  }
}

// ---------------- split-K combine ----------------
__global__ __launch_bounds__(64) void flash_combine(const char* __restrict__ part,
                                                    ushort* __restrict__ Y) {
  const int qg = blockIdx.x, h = blockIdx.y, d = threadIdx.x;
  const int qrow0 = qg * 16;
  const int nch = (qrow0 + 16 + 1023) >> 10;
  const char* ub = part + ((long)(h * 256 + qg)) * 4 * 2176;
  float Mg[16];
#pragma unroll
  for (int r = 0; r < 16; ++r) Mg[r] = -1e30f;
  for (int cc = 0; cc < nch; ++cc) {
    const float* mp = (const float*)(ub + cc * 2176 + 2048);
#pragma unroll
    for (int r = 0; r < 16; ++r) Mg[r] = fmaxf(Mg[r], mp[r]);
  }
  float acc[16], lg[16];
#pragma unroll
  for (int r = 0; r < 16; ++r) { acc[r] = 0.0f; lg[r] = 0.0f; }
  for (int cc = 0; cc < nch; ++cc) {
    const ushort* op = (const ushort*)(ub + cc * 2176);
    const float* mp = (const float*)(ub + cc * 2176 + 2048);
    const float* lp = (const float*)(ub + cc * 2176 + 2112);
#pragma unroll
    for (int r = 0; r < 16; ++r) {
      float wgt = EXP2F(mp[r] - Mg[r]);
      acc[r] += wgt * b2f(op[r * 64 + d]);
      lg[r]  += wgt * lp[r];
    }
  }
#pragma unroll
  for (int r = 0; r < 16; ++r)
    Y[(long)(qrow0 + r) * 768 + h * 64 + d] = f2b(acc[r] / lg[r]);
}

extern "C" void kernel_launch(void* const* d_in, const int* in_sizes, int n_in,
                              void* d_out, int out_size, void* d_ws, size_t ws_size,
                              hipStream_t stream) {
  const float* x      = (const float*)d_in[0];
  const float* w_attn = (const float*)d_in[1];
  const float* w_proj = (const float*)d_in[2];
  float* out = (float*)d_out;
  char* ws = (char*)d_ws;

  ushort* xb   = (ushort*)(ws);                 // 4096*768
  ushort* wAb  = (ushort*)(ws + 6291456);       // 2304*768
  ushort* wPb  = (ushort*)(ws + 9830400);       // 768*768
  float*  cosT = (float*)(ws + 11010048);       // 4096*32
  float*  sinT = (float*)(ws + 11534336);
  char*   partR = (ws + 12058624);              // flash split-K partials
  ushort* Qb   = (ushort*)(ws + 49807360);      // [12][4096][64]
  ushort* Kbb  = (ushort*)(ws + 56098816);
  ushort* Vt   = (ushort*)(ws + 62390272);      // [12][64][4096]
  ushort* Yb   = (ushort*)(ws + 68681728);      // [4096][768]

  prep_all<<<2752, 256, 0, stream>>>(x, w_attn, w_proj, xb, wAb, wPb, cosT, sinT);
  gemm_qkv<<<576, 256, 0, stream>>>(xb, wAb, cosT, sinT, Qb, Kbb, Vt);
  flash_attn<<<960, 512, 0, stream>>>(Qb, Kbb, Vt, partR);
  flash_combine<<<dim3(256, NH), 64, 0, stream>>>(partR, Yb);
  gemm_bt<<<192, 256, 0, stream>>>(Yb, wPb, out, 4096, 768, 768);
}